// Round 1
// baseline (1243.677 us; speedup 1.0000x reference)
//
#include <hip/hip_runtime.h>

#define BB   8
#define CC   64
#define HH   128
#define WW   128
#define OCC  128
#define HWx  (HH*WW)
#define NOFF 18
#define TP   16
#define SSTR 580   // 576 + 4 pad: breaks 16-way bank conflict on per-pixel rows

// ---------------- K1: offset conv (channels 0..17 only), stride 1, pad 1 ----
// grid: BB*(HH/2) blocks, 256 threads = 2 rows x 128 cols
__global__ __launch_bounds__(256) void koff(const float* __restrict__ x,
                                            const float* __restrict__ off_w,
                                            const float* __restrict__ off_b,
                                            float* __restrict__ offs) {
    __shared__ float wl[576][20];   // [c*9+di*3+dj][ch], ch padded 18->20 (46 KB)
    int tid = threadIdx.x;
    for (int idx = tid; idx < 18 * 576; idx += 256) {
        int ch = idx / 576;
        int r  = idx % 576;
        wl[r][ch] = off_w[ch * 576 + r];
    }
    __syncthreads();

    int b  = blockIdx.x / (HH / 2);
    int i  = (blockIdx.x % (HH / 2)) * 2 + (tid >> 7);
    int j  = tid & 127;
    const float* xb = x + b * CC * HWx;

    float acc[18];
#pragma unroll
    for (int ch = 0; ch < 18; ++ch) acc[ch] = off_b[ch];

    for (int c = 0; c < CC; ++c) {
        const float* xc = xb + c * HWx;
#pragma unroll
        for (int di = 0; di < 3; ++di) {
            int r = i + di - 1;
            bool rv = (r >= 0) && (r < HH);
#pragma unroll
            for (int dj = 0; dj < 3; ++dj) {
                int s = j + dj - 1;
                float xv = (rv && s >= 0 && s < WW) ? xc[r * WW + s] : 0.f;
                const float* wrow = &wl[c * 9 + di * 3 + dj][0];
#pragma unroll
                for (int ch = 0; ch < 18; ++ch)
                    acc[ch] = fmaf(xv, wrow[ch], acc[ch]);
            }
        }
    }
    float* ob = offs + (b * NOFF) * HWx + i * WW + j;
#pragma unroll
    for (int ch = 0; ch < 18; ++ch) ob[ch * HWx] = acc[ch];
}

// ---------------- K2: fused bilinear-sample + stride-3 conv --------------
// Each output (oi,oj) tap (kr,kc) maps to sample at pixel
// (oi - (kr==0), oj - (kc==0)) with n = nrow*3+ncol, nrow=(kr==0?2:kr-1).
// grid: BB*HH*(WW/TP) = 8192 blocks, 256 threads.
__global__ __launch_bounds__(256) void kmain(const float* __restrict__ x,
                                             const float* __restrict__ offs,
                                             const float* __restrict__ conv_w,
                                             const float* __restrict__ conv_b,
                                             float* __restrict__ out) {
    __shared__ float S[TP][SSTR];   // 37.1 KB, S[p][c*9 + kr*3 + kc]
    int tid = threadIdx.x;
    int bi  = blockIdx.x;
    int b   = bi >> 10;             // / (128 rows * 8 col-tiles)
    int rem = bi & 1023;
    int oi  = rem >> 3;
    int oj0 = (rem & 7) * TP;

    const float* xb   = x + b * CC * HWx;
    const float* offb = offs + b * NOFF * HWx;

    // ---- phase 1: build sample matrix in LDS ----
    int pix = tid & 15;
    int cg  = tid >> 4;             // 0..15
    int oj  = oj0 + pix;
#pragma unroll
    for (int tap = 0; tap < 9; ++tap) {
        int kr = tap / 3, kc = tap % 3;
        int si = oi + ((kr == 0) ? -1 : 0);
        int sj = oj + ((kc == 0) ? -1 : 0);
        int k1 = (kr == 0) ? 2 : kr - 1;
        int k2 = (kc == 0) ? 2 : kc - 1;
        int n  = k1 * 3 + k2;

        if (si < 0 || sj < 0) {     // zero-pad row/col of the upsampled image
#pragma unroll
            for (int u = 0; u < 4; ++u) {
                int c = u * 16 + cg;
                S[pix][c * 9 + tap] = 0.f;
            }
            continue;
        }

        float ox = offb[n * HWx + si * WW + sj];
        float oy = offb[(n + 9) * HWx + si * WW + sj];
        float px = (float)si + ox;
        float py = (float)sj + oy;
        float fx = floorf(px), fy = floorf(py);
        float pxc   = fminf(fmaxf(px, 0.f), 127.f);
        float pyc   = fminf(fmaxf(py, 0.f), 127.f);
        float qltxf = fminf(fmaxf(fx, 0.f), 127.f);
        float qltyf = fminf(fmaxf(fy, 0.f), 127.f);
        float qrbxf = fminf(fmaxf(fx + 1.f, 0.f), 127.f);
        float qrbyf = fminf(fmaxf(fy + 1.f, 0.f), 127.f);
        int qltx = (int)qltxf, qlty = (int)qltyf;
        int qrbx = (int)qrbxf, qrby = (int)qrbyf;
        float glt = (1.f + (qltxf - pxc)) * (1.f + (qltyf - pyc));
        float grb = (1.f - (qrbxf - pxc)) * (1.f - (qrbyf - pyc));
        float glb = (1.f + (qltxf - pxc)) * (1.f - (qrbyf - pyc));
        float grt = (1.f - (qrbxf - pxc)) * (1.f + (qltyf - pyc));
        int alt = qltx * WW + qlty;
        int arb = qrbx * WW + qrby;
        int alb = qltx * WW + qrby;
        int art = qrbx * WW + qlty;
#pragma unroll
        for (int u = 0; u < 4; ++u) {
            int c = u * 16 + cg;
            const float* xc = xb + c * HWx;
            float v = glt * xc[alt] + grb * xc[arb] + glb * xc[alb] + grt * xc[art];
            S[pix][c * 9 + tap] = v;
        }
    }
    __syncthreads();

    // ---- phase 2: 128-oc x 16-pix x 576-K dot ----
    int ocg = tid >> 4;             // 0..15, owns oc = u*16 + ocg
    float acc[8];
#pragma unroll
    for (int u = 0; u < 8; ++u) acc[u] = conv_b[u * 16 + ocg];

    for (int kk = 0; kk < 576; kk += 4) {
        float4 sv = *(const float4*)&S[pix][kk];
#pragma unroll
        for (int u = 0; u < 8; ++u) {
            int oc = u * 16 + ocg;
            float4 wv = *(const float4*)&conv_w[oc * 576 + kk];
            acc[u] = fmaf(sv.x, wv.x, acc[u]);
            acc[u] = fmaf(sv.y, wv.y, acc[u]);
            acc[u] = fmaf(sv.z, wv.z, acc[u]);
            acc[u] = fmaf(sv.w, wv.w, acc[u]);
        }
    }

    float* ob = out + ((size_t)(b * OCC) * HH + oi) * WW + oj;
#pragma unroll
    for (int u = 0; u < 8; ++u) {
        int oc = u * 16 + ocg;
        ob[(size_t)oc * HWx] = acc[u];
    }
}

extern "C" void kernel_launch(void* const* d_in, const int* in_sizes, int n_in,
                              void* d_out, int out_size, void* d_ws, size_t ws_size,
                              hipStream_t stream) {
    const float* x      = (const float*)d_in[0];
    const float* off_w  = (const float*)d_in[1];
    const float* off_b  = (const float*)d_in[2];
    const float* conv_w = (const float*)d_in[3];
    const float* conv_b = (const float*)d_in[4];
    float* out  = (float*)d_out;
    float* offs = (float*)d_ws;     // 8*18*128*128*4 = 9.44 MB scratch

    koff<<<BB * (HH / 2), 256, 0, stream>>>(x, off_w, off_b, offs);
    kmain<<<BB * HH * (WW / TP), 256, 0, stream>>>(x, offs, conv_w, conv_b, out);
}

// Round 3
// 295.511 us; speedup vs baseline: 4.2086x; 4.2086x over previous
//
#include <hip/hip_runtime.h>

#define BB   8
#define CC   64
#define HH   128
#define WW   128
#define OCC  128
#define HWx  (HH*WW)
#define NOFF 18
#define KTOT 576
#define SSTRB 584   // bf16 elems per pixel row in LDS: 576 + 8 pad (2-way alias only)

typedef __attribute__((ext_vector_type(8))) short short8t;
typedef __attribute__((ext_vector_type(4))) float f32x4;

static __device__ __forceinline__ ushort f2bf(float f) {
    uint u = __float_as_uint(f);
    uint r = (u + 0x7fffu + ((u >> 16) & 1u)) >> 16;   // RNE
    return (ushort)r;
}

// ---------------- K0: conv_w fp32 -> bf16 (one-time per launch) -------------
__global__ __launch_bounds__(256) void kprep(const float* __restrict__ w,
                                             ushort* __restrict__ wb) {
    int i = blockIdx.x * 256 + threadIdx.x;   // 128*576 = 73728 total
    wb[i] = f2bf(w[i]);
}

// ---------------- K1: offset conv (channels 0..17 only), stride 1, pad 1 ----
__global__ __launch_bounds__(256) void koff(const float* __restrict__ x,
                                            const float* __restrict__ off_w,
                                            const float* __restrict__ off_b,
                                            float* __restrict__ offs) {
    __shared__ float wl[576][20];
    int tid = threadIdx.x;
    for (int idx = tid; idx < 18 * 576; idx += 256) {
        int ch = idx / 576;
        int r  = idx % 576;
        wl[r][ch] = off_w[ch * 576 + r];
    }
    __syncthreads();

    int b  = blockIdx.x / (HH / 2);
    int i  = (blockIdx.x % (HH / 2)) * 2 + (tid >> 7);
    int j  = tid & 127;
    const float* xb = x + b * CC * HWx;

    float acc[18];
#pragma unroll
    for (int ch = 0; ch < 18; ++ch) acc[ch] = off_b[ch];

    for (int c = 0; c < CC; ++c) {
        const float* xc = xb + c * HWx;
#pragma unroll
        for (int di = 0; di < 3; ++di) {
            int r = i + di - 1;
            bool rv = (r >= 0) && (r < HH);
#pragma unroll
            for (int dj = 0; dj < 3; ++dj) {
                int s = j + dj - 1;
                float xv = (rv && s >= 0 && s < WW) ? xc[r * WW + s] : 0.f;
                const float* wrow = &wl[c * 9 + di * 3 + dj][0];
#pragma unroll
                for (int ch = 0; ch < 18; ++ch)
                    acc[ch] = fmaf(xv, wrow[ch], acc[ch]);
            }
        }
    }
    float* ob = offs + (b * NOFF) * HWx + i * WW + j;
#pragma unroll
    for (int ch = 0; ch < 18; ++ch) ob[ch * HWx] = acc[ch];
}

// ---------------- K2: fused bilinear-sample + MFMA stride-3 conv ------------
// Block: 256 threads (4 waves), 32 output pixels of one row, all 128 oc.
// grid = 8 * 128 * 4 = 4096.
__global__ __launch_bounds__(256) void kmain2(const float* __restrict__ x,
                                              const float* __restrict__ offs,
                                              const ushort* __restrict__ wb,
                                              const float* __restrict__ conv_b,
                                              float* __restrict__ out) {
    __shared__ ushort S[32 * SSTRB];   // 37376 B, S[pix][k], k = c*9 + tap
    int tid = threadIdx.x;
    int bi  = blockIdx.x;
    int b   = bi >> 9;                 // / (128 rows * 4 tiles)
    int rem = bi & 511;
    int oi  = rem >> 2;
    int oj0 = (rem & 3) * 32;

    const float* xb   = x + b * CC * HWx;
    const float* offb = offs + b * NOFF * HWx;

    // ---- phase 1: build 32x576 bf16 sample matrix in LDS ----
    {
        int pix = tid & 31;
        int cg  = tid >> 5;            // 0..7, owns channels cg*8 .. cg*8+7
        int oj  = oj0 + pix;
#pragma unroll
        for (int tap = 0; tap < 9; ++tap) {
            int kr = tap / 3, kc = tap % 3;
            int si = oi + ((kr == 0) ? -1 : 0);
            int sj = oj + ((kc == 0) ? -1 : 0);
            int k1 = (kr == 0) ? 2 : kr - 1;
            int k2 = (kc == 0) ? 2 : kc - 1;
            int n  = k1 * 3 + k2;

            if (si < 0 || sj < 0) {    // zero-pad of the upsampled image
#pragma unroll
                for (int u = 0; u < 8; ++u) {
                    int c = cg * 8 + u;
                    S[pix * SSTRB + c * 9 + tap] = 0;
                }
                continue;
            }

            float ox = offb[n * HWx + si * WW + sj];
            float oy = offb[(n + 9) * HWx + si * WW + sj];
            float px = (float)si + ox;
            float py = (float)sj + oy;
            float fx = floorf(px), fy = floorf(py);
            float pxc   = fminf(fmaxf(px, 0.f), 127.f);
            float pyc   = fminf(fmaxf(py, 0.f), 127.f);
            float qltxf = fminf(fmaxf(fx, 0.f), 127.f);
            float qltyf = fminf(fmaxf(fy, 0.f), 127.f);
            float qrbxf = fminf(fmaxf(fx + 1.f, 0.f), 127.f);
            float qrbyf = fminf(fmaxf(fy + 1.f, 0.f), 127.f);
            int qltx = (int)qltxf, qlty = (int)qltyf;
            int qrbx = (int)qrbxf, qrby = (int)qrbyf;
            float glt = (1.f + (qltxf - pxc)) * (1.f + (qltyf - pyc));
            float grb = (1.f - (qrbxf - pxc)) * (1.f - (qrbyf - pyc));
            float glb = (1.f + (qltxf - pxc)) * (1.f - (qrbyf - pyc));
            float grt = (1.f - (qrbxf - pxc)) * (1.f + (qltyf - pyc));
            int alt = qltx * WW + qlty;
            int arb = qrbx * WW + qrby;
            int alb = qltx * WW + qrby;
            int art = qrbx * WW + qlty;
#pragma unroll
            for (int u = 0; u < 8; ++u) {
                int c = cg * 8 + u;
                const float* xc = xb + c * HWx;
                float v = glt * xc[alt] + grb * xc[arb] + glb * xc[alb] + grt * xc[art];
                S[pix * SSTRB + c * 9 + tap] = f2bf(v);
            }
        }
    }
    __syncthreads();

    // ---- phase 2: 128oc x 32pix x 576K GEMM via mfma_f32_16x16x32_bf16 ----
    int wv = tid >> 6;                 // wave 0..3: oc rows [32*wv, 32*wv+32)
    int l  = tid & 63;
    int lr = l & 15;                   // A row / B col / D col
    int lg = l >> 4;                   // k-group / D row group

    f32x4 acc[2][2];                   // [oc-tile a][pix-tile p]
#pragma unroll
    for (int a = 0; a < 2; ++a) {
        int ocb = 16 * (2 * wv + a) + lg * 4;
#pragma unroll
        for (int e = 0; e < 4; ++e) {
            float bv = conv_b[ocb + e];
            acc[a][0][e] = bv;
            acc[a][1][e] = bv;
        }
    }

    const ushort* wr0 = wb + (size_t)(16 * (2 * wv + 0) + lr) * KTOT + lg * 8;
    const ushort* wr1 = wb + (size_t)(16 * (2 * wv + 1) + lr) * KTOT + lg * 8;
    const ushort* s0  = &S[(lr) * SSTRB + lg * 8];
    const ushort* s1  = &S[(16 + lr) * SSTRB + lg * 8];

    for (int ks = 0; ks < 18; ++ks) {
        int kk = ks * 32;
        short8t a0 = *(const short8t*)(wr0 + kk);
        short8t a1 = *(const short8t*)(wr1 + kk);
        short8t b0 = *(const short8t*)(s0 + kk);
        short8t b1 = *(const short8t*)(s1 + kk);
        acc[0][0] = __builtin_amdgcn_mfma_f32_16x16x32_bf16(a0, b0, acc[0][0], 0, 0, 0);
        acc[0][1] = __builtin_amdgcn_mfma_f32_16x16x32_bf16(a0, b1, acc[0][1], 0, 0, 0);
        acc[1][0] = __builtin_amdgcn_mfma_f32_16x16x32_bf16(a1, b0, acc[1][0], 0, 0, 0);
        acc[1][1] = __builtin_amdgcn_mfma_f32_16x16x32_bf16(a1, b1, acc[1][1], 0, 0, 0);
    }

    // ---- store: D row=(lg*4+e) within oc-tile, col=lr within pix-tile ----
    float* ob = out + ((size_t)b * OCC * HH + oi) * WW + oj0;
#pragma unroll
    for (int a = 0; a < 2; ++a) {
        int ocb = 16 * (2 * wv + a) + lg * 4;
#pragma unroll
        for (int p = 0; p < 2; ++p) {
#pragma unroll
            for (int e = 0; e < 4; ++e) {
                int oc  = ocb + e;
                int col = 16 * p + lr;
                ob[(size_t)oc * HWx + col] = acc[a][p][e];
            }
        }
    }
}

extern "C" void kernel_launch(void* const* d_in, const int* in_sizes, int n_in,
                              void* d_out, int out_size, void* d_ws, size_t ws_size,
                              hipStream_t stream) {
    const float* x      = (const float*)d_in[0];
    const float* off_w  = (const float*)d_in[1];
    const float* off_b  = (const float*)d_in[2];
    const float* conv_w = (const float*)d_in[3];
    const float* conv_b = (const float*)d_in[4];
    float* out  = (float*)d_out;

    ushort* wbf = (ushort*)d_ws;                          // 147456 B
    float*  offs = (float*)((char*)d_ws + 147456);        // 9.44 MB

    kprep<<<(OCC * KTOT) / 256, 256, 0, stream>>>(conv_w, wbf);
    koff<<<BB * (HH / 2), 256, 0, stream>>>(x, off_w, off_b, offs);
    kmain2<<<BB * HH * (WW / 32), 256, 0, stream>>>(x, offs, wbf, conv_b, out);
}